// Round 4
// baseline (271.609 us; speedup 1.0000x reference)
//
#include <hip/hip_runtime.h>
#include <math.h>

#define PATCH 96
#define STRIDE 48
#define NH 21
#define NW 21
#define NP (NH * NW)              // 441 patches per (b,c)
#define BATCH 8
#define CHAN 4
#define NBC (BATCH * CHAN)        // 32
#define IMG_H 1056
#define IMG_W 1056
#define NBAND 22                  // 48-row bands
#define NCHUNK 22                 // 48-col chunks
#define NSTAT 6                   // s1, s2, gxi, gxb, gyi, gyb
#define NPIX 9216.0f
#define NGRAD 9120.0f

typedef float f32x4 __attribute__((ext_vector_type(4)));

__device__ __forceinline__ f32x4 ntload4(const float* p) {
  return __builtin_nontemporal_load((const f32x4*)p);
}

// ---------------------------------------------------------------------------
// Phase 1: one block per (bc, band). 264 active threads (of 320) each own 4
// contiguous cols across all 48(+1) rows. One nontemporal float4 load per row
// per thread; the cross-thread gx diff comes from __shfl_up(A.w,1); only the
// 5 lane-0 threads do a predicated scalar load of col-1. Left-boundary diffs
// (thread tc%12==0) are attributed to chunk m-1's gxb slot via LDS atomics.
// ---------------------------------------------------------------------------
__global__ __launch_bounds__(320) void band_stats_kernel(
    const float* __restrict__ x, float* __restrict__ pf) {
  __shared__ float acc[NCHUNK * NSTAT];   // 528 B

  const int t = threadIdx.x;              // 0..319
  const int bc = blockIdx.x / NBAND;
  const int band = blockIdx.x - bc * NBAND;
  const bool active = t < 264;
  const int tc = active ? t : 263;        // clamp idle lanes to a safe column
  const int lane = t & 63;
  const bool lane0 = (lane == 0);

  const float* rowbase = x + (size_t)bc * (IMG_H * IMG_W)
                           + (size_t)(band * STRIDE) * IMG_W
                           + (size_t)(4 * tc);

  float s1 = 0.f, s2 = 0.f, gxi = 0.f, dla = 0.f, gyi = 0.f, gyb = 0.f;

  // Per row: s1/s2 over own 4 cols; gx internal diffs d1..d3; left diff
  // dl = A.x - (left neighbor col 4tc-1), accumulated separately in dla.
#define ROW_SUMS(A, sh)                                                  \
  do {                                                                   \
    s1 += (A).x + (A).y + (A).z + (A).w;                                 \
    s2 += (A).x * (A).x + (A).y * (A).y + (A).z * (A).z + (A).w * (A).w; \
    float d1 = (A).y - (A).x, d2 = (A).z - (A).y, d3 = (A).w - (A).z;    \
    gxi += d1 * d1 + d2 * d2 + d3 * d3;                                  \
    float dl = (A).x - (sh);                                             \
    dla += dl * dl;                                                      \
  } while (0)

  f32x4 prev;
  {  // row 0
    f32x4 A = ntload4(rowbase);
    float sh = __shfl_up(A.w, 1);
    if (lane0) sh = (tc > 0) ? rowbase[-1] : A.x;   // tc==0 -> dl = 0
    ROW_SUMS(A, sh);
    prev = A;
  }
#pragma unroll 6
  for (int r = 1; r < 48; ++r) {
    const float* rp = rowbase + (size_t)r * IMG_W;
    f32x4 A = ntload4(rp);
    float sh = __shfl_up(A.w, 1);
    if (lane0) sh = (tc > 0) ? rp[-1] : A.x;
    ROW_SUMS(A, sh);
    float e0 = A.x - prev.x, e1 = A.y - prev.y,
          e2 = A.z - prev.z, e3 = A.w - prev.w;
    gyi += e0 * e0 + e1 * e1 + e2 * e2 + e3 * e3;
    prev = A;
  }
  if (band != NBAND - 1) {   // boundary gy pair (47,48); absent for last band
    f32x4 A = ntload4(rowbase + (size_t)48 * IMG_W);
    float e0 = A.x - prev.x, e1 = A.y - prev.y,
          e2 = A.z - prev.z, e3 = A.w - prev.w;
    gyb = e0 * e0 + e1 * e1 + e2 * e2 + e3 * e3;
  }
#undef ROW_SUMS

  for (int i = t; i < NCHUNK * NSTAT; i += 320) acc[i] = 0.f;
  __syncthreads();
  if (active) {
    const int m = tc / 12;
    const bool left_is_boundary = ((tc % 12) == 0);
    float gxi_tot = gxi + (left_is_boundary ? 0.f : dla);
    atomicAdd(&acc[m * NSTAT + 0], s1);
    atomicAdd(&acc[m * NSTAT + 1], s2);
    atomicAdd(&acc[m * NSTAT + 2], gxi_tot);
    atomicAdd(&acc[m * NSTAT + 4], gyi);
    atomicAdd(&acc[m * NSTAT + 5], gyb);
    if (left_is_boundary && tc > 0)
      atomicAdd(&acc[(m - 1) * NSTAT + 3], dla);   // boundary (m-1)->m
  }
  __syncthreads();
  float* dst = pf + (size_t)(bc * NBAND + band) * (NCHUNK * NSTAT);
  for (int i = t; i < NCHUNK * NSTAT; i += 320) dst[i] = acc[i];
}

// ---------------------------------------------------------------------------
// Phase 2: one block per bc. Stage the bc's 22x22x6 slab in LDS; thread p<441
// combines its 2x2 cells into (mu, var, gmag); block-reduce to per-bc means.
// ---------------------------------------------------------------------------
__global__ __launch_bounds__(512) void patch_feats_kernel(
    const float* __restrict__ pf, float* __restrict__ featsG) {
  __shared__ float S[NBAND * NCHUNK * NSTAT];   // 11.6 KB
  __shared__ float wsum[8][3];

  const int bc = blockIdx.x;
  const int t = threadIdx.x;
  const float* src = pf + (size_t)bc * (NBAND * NCHUNK * NSTAT);
  for (int i = t; i < NBAND * NCHUNK * NSTAT; i += 512) S[i] = src[i];
  __syncthreads();

  float fmu = 0.f, fvar = 0.f, fg = 0.f;
  if (t < NP) {
    const int ph = t / NW, pw = t - ph * NW;
#define AT(b, c, s) S[((b) * NCHUNK + (c)) * NSTAT + (s)]
    float S1 = AT(ph, pw, 0) + AT(ph, pw + 1, 0) + AT(ph + 1, pw, 0) + AT(ph + 1, pw + 1, 0);
    float S2 = AT(ph, pw, 1) + AT(ph, pw + 1, 1) + AT(ph + 1, pw, 1) + AT(ph + 1, pw + 1, 1);
    float Gx = AT(ph, pw, 2) + AT(ph, pw, 3) + AT(ph, pw + 1, 2)
             + AT(ph + 1, pw, 2) + AT(ph + 1, pw, 3) + AT(ph + 1, pw + 1, 2);
    float Gy = AT(ph, pw, 4) + AT(ph, pw, 5) + AT(ph + 1, pw, 4)
             + AT(ph, pw + 1, 4) + AT(ph, pw + 1, 5) + AT(ph + 1, pw + 1, 4);
#undef AT
    fmu = S1 / NPIX;
    fvar = (S2 - S1 * S1 / NPIX) / (NPIX - 1.f);
    fg = sqrtf((Gx + Gy) / NGRAD);
  }
#pragma unroll
  for (int off = 32; off > 0; off >>= 1) {
    fmu += __shfl_xor(fmu, off);
    fvar += __shfl_xor(fvar, off);
    fg += __shfl_xor(fg, off);
  }
  const int wave = t >> 6;
  if ((t & 63) == 0) { wsum[wave][0] = fmu; wsum[wave][1] = fvar; wsum[wave][2] = fg; }
  __syncthreads();
  if (t == 0) {
    float m = 0.f, v = 0.f, g = 0.f;
#pragma unroll
    for (int w = 0; w < 8; ++w) { m += wsum[w][0]; v += wsum[w][1]; g += wsum[w][2]; }
    const int b = bc / CHAN, c = bc - b * CHAN;
    featsG[b * 12 + 0 + c] = m / (float)NP;
    featsG[b * 12 + 4 + c] = v / (float)NP;
    featsG[b * 12 + 8 + c] = g / (float)NP;
  }
}

// ---------------------------------------------------------------------------
// Finalize: ONE wave. Register-resident Gauss-Jordan on the augmented 12x24
// system: lane c<24 owns column c (12 f64 registers); pivot row values are
// broadcast with __shfl from lane k (cov is SPD -> no pivoting needed at fp32
// tolerance). Then Mahalanobis per batch + mean.
// ---------------------------------------------------------------------------
__global__ __launch_bounds__(64) void finalize_kernel(
    const float* __restrict__ featsG, const float* __restrict__ mu0_full,
    const float* __restrict__ cov_full, float* __restrict__ out) {
  __shared__ float feats_s[96];
  __shared__ double inv_s[12][12];
  __shared__ float dist[BATCH];

  const int t = threadIdx.x;   // one wave: 0..63
  feats_s[t] = featsG[t];
  if (t < 32) feats_s[64 + t] = featsG[64 + t];

  double M[12];
#pragma unroll
  for (int r = 0; r < 12; ++r) {
    double v = 0.0;
    if (t < 12) v = (double)cov_full[r * 36 + t];
    else if (t < 24) v = (t - 12 == r) ? 1.0 : 0.0;
    M[r] = v;
  }

#pragma unroll
  for (int k = 0; k < 12; ++k) {
    const double piv = __shfl(M[k], k);
    const double ip = 1.0 / piv;
    M[k] *= ip;
#pragma unroll
    for (int r = 0; r < 12; ++r) {
      if (r == k) continue;
      const double f = __shfl(M[r], k);   // old M[r][k], read before update
      M[r] -= f * M[k];
    }
  }

  if (t >= 12 && t < 24) {
    const int j = t - 12;
#pragma unroll
    for (int r = 0; r < 12; ++r) inv_s[r][j] = M[r];
  }
  __syncthreads();

  if (t < BATCH) {
    double acc = 0.0;
    double d[12];
#pragma unroll
    for (int i = 0; i < 12; ++i)
      d[i] = (double)feats_s[t * 12 + i] - (double)mu0_full[i];
#pragma unroll
    for (int i = 0; i < 12; ++i) {
      double row = 0.0;
#pragma unroll
      for (int j = 0; j < 12; ++j) row += inv_s[i][j] * d[j];
      acc += d[i] * row;
    }
    dist[t] = (float)sqrt(acc);
  }
  __syncthreads();
  if (t == 0) {
    float m = 0.f;
#pragma unroll
    for (int b = 0; b < BATCH; ++b) m += dist[b];
    out[0] = m / (float)BATCH;
  }
}

extern "C" void kernel_launch(void* const* d_in, const int* in_sizes, int n_in,
                              void* d_out, int out_size, void* d_ws, size_t ws_size,
                              hipStream_t stream) {
  const float* x   = (const float*)d_in[0];
  const float* mu0 = (const float*)d_in[1];
  const float* cov = (const float*)d_in[2];
  float* out = (float*)d_out;
  float* pf     = (float*)d_ws;                                   // 32*22*132 floats = 371.7 KB
  float* featsG = pf + (size_t)NBC * NBAND * NCHUNK * NSTAT;      // 96 floats

  band_stats_kernel<<<NBC * NBAND, 320, 0, stream>>>(x, pf);
  patch_feats_kernel<<<NBC, 512, 0, stream>>>(pf, featsG);
  finalize_kernel<<<1, 64, 0, stream>>>(featsG, mu0, cov, out);
}

// Round 5
// 224.675 us; speedup vs baseline: 1.2089x; 1.2089x over previous
//
#include <hip/hip_runtime.h>
#include <math.h>

#define PATCH 96
#define STRIDE 48
#define NH 21
#define NW 21
#define NP (NH * NW)              // 441 patches per (b,c)
#define BATCH 8
#define CHAN 4
#define NBC (BATCH * CHAN)        // 32
#define IMG_H 1056
#define IMG_W 1056
#define NHB 44                    // 24-row half-bands
#define NCHUNK 22                 // 48-col chunks
#define NSTAT 6                   // s1, s2, gxi, gxb, gyi, gyb
#define NPIX 9216.0f
#define NGRAD 9120.0f

// ---------------------------------------------------------------------------
// Phase 1: one block per (bc, half-band). 264 active threads (of 320) own 4
// contiguous cols across 24 rows (+1 boundary row for gy). Plain float4 load
// + one overlapping scalar load for the right gx neighbor (L1 hit). Per-chunk
// partials merged via LDS atomics; 132 floats per block.
//   gxi: horizontal diffs internal to chunk; gxb: boundary diff chunk m->m+1
//   gyi: 23 vertical pairs inside the half-band; gyb: boundary pair to the
//        first row of the next half-band (absent for hb==43)
// ---------------------------------------------------------------------------
__global__ __launch_bounds__(320) void band_stats_kernel(
    const float* __restrict__ x, float* __restrict__ pf) {
  __shared__ float acc[NCHUNK * NSTAT];   // 528 B

  const int t = threadIdx.x;              // 0..319
  const int bc = blockIdx.x / NHB;
  const int hb = blockIdx.x - bc * NHB;
  const bool active = t < 264;
  const int tc = active ? t : 263;        // clamp idle lanes to a safe column
  // right-neighbor offset: +4 except at image edge (clamped -> d4==0, lands
  // in the never-read gxb of chunk 21)
  const int noff = (tc == 263) ? 3 : 4;

  const float* rowbase = x + (size_t)bc * (IMG_H * IMG_W)
                           + (size_t)(hb * 24) * IMG_W
                           + (size_t)(4 * tc);

  float s1 = 0.f, s2 = 0.f, gxi = 0.f, gxb = 0.f, gyi = 0.f, gyb = 0.f;
  const bool bnd_is_gxb = ((tc % 12) == 11);   // last quad of its chunk

#define SUMS_GX(A, nxt)                                                  \
  do {                                                                   \
    s1 += (A).x + (A).y + (A).z + (A).w;                                 \
    s2 += (A).x * (A).x + (A).y * (A).y + (A).z * (A).z + (A).w * (A).w; \
    float d1 = (A).y - (A).x, d2 = (A).z - (A).y, d3 = (A).w - (A).z;    \
    float d4 = (nxt) - (A).w;                                            \
    gxi += d1 * d1 + d2 * d2 + d3 * d3;                                  \
    float bd = d4 * d4;                                                  \
    if (bnd_is_gxb) gxb += bd; else gxi += bd;                           \
  } while (0)

  float4 prev;
  {  // row 0 (no gy)
    const float4 A = *(const float4*)rowbase;
    const float nxt = rowbase[noff];
    SUMS_GX(A, nxt);
    prev = A;
  }
#pragma unroll 4
  for (int r = 1; r < 24; ++r) {
    const float4 A = *(const float4*)(rowbase + (size_t)r * IMG_W);
    const float nxt = rowbase[(size_t)r * IMG_W + noff];
    SUMS_GX(A, nxt);
    const float e0 = A.x - prev.x, e1 = A.y - prev.y,
                e2 = A.z - prev.z, e3 = A.w - prev.w;
    gyi += e0 * e0 + e1 * e1 + e2 * e2 + e3 * e3;
    prev = A;
  }
  if (hb != NHB - 1) {   // boundary gy pair (row 23 <-> row 24 == next hb's row 0)
    const float4 A = *(const float4*)(rowbase + (size_t)24 * IMG_W);
    const float e0 = A.x - prev.x, e1 = A.y - prev.y,
                e2 = A.z - prev.z, e3 = A.w - prev.w;
    gyb = e0 * e0 + e1 * e1 + e2 * e2 + e3 * e3;
  }
#undef SUMS_GX

  for (int i = t; i < NCHUNK * NSTAT; i += 320) acc[i] = 0.f;
  __syncthreads();
  if (active) {
    const int chunk = tc / 12;
    atomicAdd(&acc[chunk * NSTAT + 0], s1);
    atomicAdd(&acc[chunk * NSTAT + 1], s2);
    atomicAdd(&acc[chunk * NSTAT + 2], gxi);
    atomicAdd(&acc[chunk * NSTAT + 3], gxb);
    atomicAdd(&acc[chunk * NSTAT + 4], gyi);
    atomicAdd(&acc[chunk * NSTAT + 5], gyb);
  }
  __syncthreads();
  float* dst = pf + (size_t)(bc * NHB + hb) * (NCHUNK * NSTAT);
  for (int i = t; i < NCHUNK * NSTAT; i += 320) dst[i] = acc[i];
}

// ---------------------------------------------------------------------------
// Phase 2: one block per bc. Stage the bc's 44x22x6 slab in LDS (23.2 KB);
// thread p<441 combines its 4 half-bands x 2 chunks into (mu, var, gmag);
// block-reduce to per-bc means.
//   patch(ph,pw): half-bands 2ph..2ph+3, chunks pw..pw+1
//   Gx = sum gxi(both chunks) + gxb(left chunk) over 4 half-bands
//   Gy = sum gyi(4 hbs) + gyb(first 3 hbs) over both chunks  (95 pairs)
// ---------------------------------------------------------------------------
__global__ __launch_bounds__(512) void patch_feats_kernel(
    const float* __restrict__ pf, float* __restrict__ featsG) {
  __shared__ float S[NHB * NCHUNK * NSTAT];   // 5808 floats = 23.2 KB
  __shared__ float wsum[8][3];

  const int bc = blockIdx.x;
  const int t = threadIdx.x;
  const float* src = pf + (size_t)bc * (NHB * NCHUNK * NSTAT);
  for (int i = t; i < NHB * NCHUNK * NSTAT; i += 512) S[i] = src[i];
  __syncthreads();

  float fmu = 0.f, fvar = 0.f, fg = 0.f;
  if (t < NP) {
    const int ph = t / NW, pw = t - ph * NW;
    const int h0 = 2 * ph;
#define AT(h, c, s) S[((h) * NCHUNK + (c)) * NSTAT + (s)]
    float S1 = 0.f, S2 = 0.f, Gx = 0.f, Gy = 0.f;
#pragma unroll
    for (int hh = 0; hh < 4; ++hh) {
      const int h = h0 + hh;
      S1 += AT(h, pw, 0) + AT(h, pw + 1, 0);
      S2 += AT(h, pw, 1) + AT(h, pw + 1, 1);
      Gx += AT(h, pw, 2) + AT(h, pw, 3) + AT(h, pw + 1, 2);
      Gy += AT(h, pw, 4) + AT(h, pw + 1, 4);
    }
#pragma unroll
    for (int hh = 0; hh < 3; ++hh) {
      const int h = h0 + hh;
      Gy += AT(h, pw, 5) + AT(h, pw + 1, 5);
    }
#undef AT
    fmu = S1 / NPIX;
    fvar = (S2 - S1 * S1 / NPIX) / (NPIX - 1.f);
    fg = sqrtf((Gx + Gy) / NGRAD);
  }
#pragma unroll
  for (int off = 32; off > 0; off >>= 1) {
    fmu += __shfl_xor(fmu, off);
    fvar += __shfl_xor(fvar, off);
    fg += __shfl_xor(fg, off);
  }
  const int wave = t >> 6;
  if ((t & 63) == 0) { wsum[wave][0] = fmu; wsum[wave][1] = fvar; wsum[wave][2] = fg; }
  __syncthreads();
  if (t == 0) {
    float m = 0.f, v = 0.f, g = 0.f;
#pragma unroll
    for (int w = 0; w < 8; ++w) { m += wsum[w][0]; v += wsum[w][1]; g += wsum[w][2]; }
    const int b = bc / CHAN, c = bc - b * CHAN;
    featsG[b * 12 + 0 + c] = m / (float)NP;
    featsG[b * 12 + 4 + c] = v / (float)NP;
    featsG[b * 12 + 8 + c] = g / (float)NP;
  }
}

// ---------------------------------------------------------------------------
// Finalize: ONE wave. Register-resident Gauss-Jordan on the augmented 12x24
// system: lane c<24 owns column c (12 f64 registers); pivot row values are
// broadcast with __shfl from lane k (cov is SPD -> no pivoting needed at fp32
// tolerance). Then Mahalanobis per batch + mean.
// ---------------------------------------------------------------------------
__global__ __launch_bounds__(64) void finalize_kernel(
    const float* __restrict__ featsG, const float* __restrict__ mu0_full,
    const float* __restrict__ cov_full, float* __restrict__ out) {
  __shared__ float feats_s[96];
  __shared__ double inv_s[12][12];
  __shared__ float dist[BATCH];

  const int t = threadIdx.x;   // one wave: 0..63
  feats_s[t] = featsG[t];
  if (t < 32) feats_s[64 + t] = featsG[64 + t];

  double M[12];
#pragma unroll
  for (int r = 0; r < 12; ++r) {
    double v = 0.0;
    if (t < 12) v = (double)cov_full[r * 36 + t];
    else if (t < 24) v = (t - 12 == r) ? 1.0 : 0.0;
    M[r] = v;
  }

#pragma unroll
  for (int k = 0; k < 12; ++k) {
    const double piv = __shfl(M[k], k);
    const double ip = 1.0 / piv;
    M[k] *= ip;
#pragma unroll
    for (int r = 0; r < 12; ++r) {
      if (r == k) continue;
      const double f = __shfl(M[r], k);   // old M[r][k], read before update
      M[r] -= f * M[k];
    }
  }

  if (t >= 12 && t < 24) {
    const int j = t - 12;
#pragma unroll
    for (int r = 0; r < 12; ++r) inv_s[r][j] = M[r];
  }
  __syncthreads();

  if (t < BATCH) {
    double acc = 0.0;
    double d[12];
#pragma unroll
    for (int i = 0; i < 12; ++i)
      d[i] = (double)feats_s[t * 12 + i] - (double)mu0_full[i];
#pragma unroll
    for (int i = 0; i < 12; ++i) {
      double row = 0.0;
#pragma unroll
      for (int j = 0; j < 12; ++j) row += inv_s[i][j] * d[j];
      acc += d[i] * row;
    }
    dist[t] = (float)sqrt(acc);
  }
  __syncthreads();
  if (t == 0) {
    float m = 0.f;
#pragma unroll
    for (int b = 0; b < BATCH; ++b) m += dist[b];
    out[0] = m / (float)BATCH;
  }
}

extern "C" void kernel_launch(void* const* d_in, const int* in_sizes, int n_in,
                              void* d_out, int out_size, void* d_ws, size_t ws_size,
                              hipStream_t stream) {
  const float* x   = (const float*)d_in[0];
  const float* mu0 = (const float*)d_in[1];
  const float* cov = (const float*)d_in[2];
  float* out = (float*)d_out;
  float* pf     = (float*)d_ws;                               // 32*44*132 floats = 743 KB
  float* featsG = pf + (size_t)NBC * NHB * NCHUNK * NSTAT;    // 96 floats

  band_stats_kernel<<<NBC * NHB, 320, 0, stream>>>(x, pf);
  patch_feats_kernel<<<NBC, 512, 0, stream>>>(pf, featsG);
  finalize_kernel<<<1, 64, 0, stream>>>(featsG, mu0, cov, out);
}